// Round 7
// baseline (26.226 us; speedup 1.0000x reference)
//
#include <hip/hip_runtime.h>
#include <math.h>

#define WINDOW_MAX 256
#define NEG -1000000.0f

typedef __attribute__((address_space(1))) const float gfloat;
typedef __attribute__((address_space(3))) float lfloat;

// raw barrier: waits only LDS ops (NOT vmcnt) -> staging loads stay in flight
#define BAR_LGKM() do { \
    asm volatile("s_waitcnt lgkmcnt(0)" ::: "memory"); \
    __builtin_amdgcn_s_barrier(); \
} while (0)

// ---------------- fast path: window==256, hd==128, 512 threads ----------------
// 2-chunk pipelined single kernel, one block per (b,h), grid (H,B) so same-h
// blocks share an XCD L2 for weight panels.
//   S-waves (4-7): issue chunk A (rows 0-127), chunk B (128-255) via
//     global_load_lds, + own Wv quarter to regs. vmcnt(48)@BA = A landed,
//     vmcnt(32)@BB = B landed. No vmcnt(0) drain in the pipeline.
//   C-waves (0-3): Wk->regs, q matvec (Wq streamed), Wv quarter, then qk.
// Chunk-A scores/exp/PV run while chunk B streams in. Softmax uses the fixed
// reference NEG as the subtract point (exact in fp32; constant factor cancels
// in normalization) so no global max reduction is needed -> chunk-local.
// xs layout: 128 floats/row, 16B-chunk XOR swizzle (lds chunk c = f ^ (row&7)).
__global__ __launch_bounds__(512, 2) void bca_fast(
    const float* __restrict__ content,   // (B, D)
    const float* __restrict__ cache,     // (B, T, D)
    const float* __restrict__ Wq,        // (H, 128, 128)
    const float* __restrict__ bq,        // (H, 128)
    const float* __restrict__ Wk,        // (H, 128, 128)
    const float* __restrict__ Wv,        // (H, 128, 128)
    const float* __restrict__ bv,        // (H, 128)
    const float* __restrict__ pos_param_p,
    float* __restrict__ out,             // (B, D)
    int B, int T, int D, int H, int S, int cutoff)
{
    constexpr int HD  = 128;
    constexpr int WIN = 256;

    __shared__ float xs[WIN * HD];       // 131072 B, swizzled 16B chunks
    __shared__ float qp[2][HD];          // q partials
    __shared__ float kp[2][HD];          // qk partials
    __shared__ float sc[128];            // chunk-local unnormalized p
    __shared__ float wp[16][HD];         // PV partials (16 s-groups)
    __shared__ float ws[HD];             // unnormalized weighted sum
    __shared__ float op[4][HD];          // out-matvec quarter partials
    __shared__ float red2[4];            // p-sum partials (2 waves x 2 chunks)

    const int tid = threadIdx.x;
    const int h = blockIdx.x, b = blockIdx.y;
    const float* cnt_g = content + (size_t)b * D + h * HD;
    const float* cb    = cache + (size_t)b * T * D + h * HD;
    const float pos_param = pos_param_p[0];

    const int e128 = tid & 127;
    const int g4   = tid >> 7;           // 0..3 wave-pair id (wave-uniform)
    const int d4   = tid & 31;           // PV: float4 chunk id
    const int sg   = tid >> 5;           // PV: s-group 0..15

    float creg = 0.f, bvreg = 0.f;
    float wvreg[32];                     // Wv[g4*32+i][e128]
    float4 wacc = make_float4(0.f, 0.f, 0.f, 0.f);

    if (tid < 256) {
        // ===== C-waves 0-3: weights + q -> qk =====
        const int g2 = g4;               // 0/1
        if (tid < HD) { creg = cnt_g[tid]; bvreg = bv[h * HD + tid]; }
        float4 wk4[16];                  // Wk[e128][g2*64 .. +63]
        {
            const float* wkp = Wk + h * HD * HD + e128 * HD + g2 * 64;
            #pragma unroll
            for (int j = 0; j < 16; ++j) wk4[j] = *(const float4*)(wkp + j * 4);
        }
        // q partial: q[e] = sum_d cnt[d] * Wq[d][e] (+ bq on g2==0 half)
        const float* wqp = Wq + h * HD * HD + (g2 * 64) * HD + e128;
        const float* cg  = cnt_g + g2 * 64;          // wave-uniform -> s_load
        float acc = (g2 == 0) ? bq[h * HD + e128] : 0.f;
        #pragma unroll
        for (int i = 0; i < 64; ++i)
            acc = fmaf(cg[i], wqp[i * HD], acc);
        // Wv quarter prefetch (issued after q stream to cap reg pressure)
        {
            const float* wvp = Wv + h * HD * HD + (g4 * 32) * HD + e128;
            #pragma unroll
            for (int i = 0; i < 32; ++i) wvreg[i] = wvp[i * HD];
        }
        qp[g2][e128] = acc;
        BAR_LGKM();                      // BA (qp visible; A landed via S-waves)

        // qk partial over e-range g2: kp[g2][d] ; qk_d = kp[0][d]+kp[1][d]
        float a2 = 0.f;
        #pragma unroll
        for (int j = 0; j < 16; ++j) {
            const float4 q0 = *(const float4*)&qp[0][g2 * 64 + j * 4];
            const float4 q1 = *(const float4*)&qp[1][g2 * 64 + j * 4];
            a2 = fmaf(wk4[j].x, q0.x + q1.x, a2);
            a2 = fmaf(wk4[j].y, q0.y + q1.y, a2);
            a2 = fmaf(wk4[j].z, q0.z + q1.z, a2);
            a2 = fmaf(wk4[j].w, q0.w + q1.w, a2);
        }
        kp[g2][e128] = a2;
        BAR_LGKM();                      // P0 (kp visible)
    } else {
        // ===== S-waves 4-7: window staging + Wv quarter =====
        const int sw   = (tid >> 6) - 4; // 0..3
        const int lane = tid & 63;
        #pragma unroll
        for (int i = 0; i < 16; ++i) {   // chunk A: rows 0..127 (< T always)
            const int w   = sw * 32 + i * 2;
            const int row = w + (lane >> 5);
            const int f   = (lane & 31) ^ (row & 7);
            const float* src = cb + (size_t)(cutoff + row) * D + f * 4;
            __builtin_amdgcn_global_load_lds((gfloat*)src, (lfloat*)&xs[w << 7],
                                             16, 0, 0);
        }
        #pragma unroll
        for (int i = 0; i < 16; ++i) {   // chunk B: rows 128..255
            const int w   = 128 + sw * 32 + i * 2;
            const int row = w + (lane >> 5);
            const int f   = (lane & 31) ^ (row & 7);
            const int gpos = cutoff + row;
            const float* src = (gpos < T) ? (cb + (size_t)gpos * D + f * 4)
                                          : (cnt_g + f * 4);
            __builtin_amdgcn_global_load_lds((gfloat*)src, (lfloat*)&xs[w << 7],
                                             16, 0, 0);
        }
        // Wv quarter prefetch (counts 32 more vmem after A16+B16)
        {
            const float* wvp = Wv + h * HD * HD + (g4 * 32) * HD + e128;
            #pragma unroll
            for (int i = 0; i < 32; ++i) wvreg[i] = wvp[i * HD];
        }
        // A done <=> >=16 oldest retired <=> <=48 outstanding (in-order count)
        asm volatile("s_waitcnt vmcnt(48)" ::: "memory");
        __builtin_amdgcn_s_barrier();    // BA
        __builtin_amdgcn_s_barrier();    // P0
    }

    // ===================== chunk A: rows 0..127 =====================
    if (tid < 128) {
        const int s = tid, s7 = s & 7;
        float dot = 0.f;
        #pragma unroll
        for (int j = 0; j < 32; ++j) {
            const int c = j ^ s7;
            const float4 x  = *(const float4*)&xs[(s << 7) + (c << 2)];
            const float4 k0 = *(const float4*)&kp[0][j * 4];   // broadcast
            const float4 k1 = *(const float4*)&kp[1][j * 4];
            dot = fmaf(x.x, k0.x + k1.x, dot);
            dot = fmaf(x.y, k0.y + k1.y, dot);
            dot = fmaf(x.z, k0.z + k1.z, dot);
            dot = fmaf(x.w, k0.w + k1.w, dot);
        }
        const int n = (WIN - 1) - s;     // 128..255: always "large" bucket
        float posb;
        if (n < 16) {
            posb = (float)n;
        } else {
            const float lc = 2.0794415416798357f;   // float32(log(8))
            int large = 16 + (int)((logf((float)n / 16.0f) / lc) * 16.0f);
            if (large > 31) large = 31;
            posb = (float)large;
        }
        // faithful quantization: +NEG (time_mask collapses to NEG everywhere),
        // then subtract NEG (exact); constant exp factor cancels in normalize.
        const float score = (dot / 11.313708498984761f) - pos_param * posb + NEG;
        const float p = expf(score - NEG);
        sc[s] = p;
        float ssum = p;
        #pragma unroll
        for (int off = 32; off >= 1; off >>= 1) ssum += __shfl_xor(ssum, off);
        if ((tid & 63) == 0) red2[tid >> 6] = ssum;      // red2[0], red2[1]
    }
    BAR_LGKM();                          // P1 (sc ready)

    // PV partial, chunk A: thread (d4, sg) accumulates rows sg*8..+7
    #pragma unroll
    for (int i = 0; i < 8; ++i) {
        const int r = sg * 8 + i;
        const int c = d4 ^ (r & 7);
        const float pw = sc[r];          // broadcast per 32-lane group
        const float4 x = *(const float4*)&xs[(r << 7) + (c << 2)];
        wacc.x = fmaf(pw, x.x, wacc.x);
        wacc.y = fmaf(pw, x.y, wacc.y);
        wacc.z = fmaf(pw, x.z, wacc.z);
        wacc.w = fmaf(pw, x.w, wacc.w);
    }
    // B done <=> >=32 oldest retired <=> <=32 outstanding (Wv may remain)
    if (tid >= 256) asm volatile("s_waitcnt vmcnt(32)" ::: "memory");
    BAR_LGKM();                          // BB (chunk B landed; sc readers done)

    // ===================== chunk B: rows 128..255 =====================
    if (tid < 128) {
        const int s = tid;
        const int r = 128 + s, s7 = r & 7;
        float dot = 0.f;
        #pragma unroll
        for (int j = 0; j < 32; ++j) {
            const int c = j ^ s7;
            const float4 x  = *(const float4*)&xs[(r << 7) + (c << 2)];
            const float4 k0 = *(const float4*)&kp[0][j * 4];
            const float4 k1 = *(const float4*)&kp[1][j * 4];
            dot = fmaf(x.x, k0.x + k1.x, dot);
            dot = fmaf(x.y, k0.y + k1.y, dot);
            dot = fmaf(x.z, k0.z + k1.z, dot);
            dot = fmaf(x.w, k0.w + k1.w, dot);
        }
        const int n = 127 - s;           // 0..127: mixed buckets
        float posb;
        if (n < 16) {
            posb = (float)n;
        } else {
            const float lc = 2.0794415416798357f;
            int large = 16 + (int)((logf((float)n / 16.0f) / lc) * 16.0f);
            if (large > 31) large = 31;
            posb = (float)large;
        }
        const float score = (dot / 11.313708498984761f) - pos_param * posb + NEG;
        const float p = expf(score - NEG);
        sc[s] = p;
        float ssum = p;
        #pragma unroll
        for (int off = 32; off >= 1; off >>= 1) ssum += __shfl_xor(ssum, off);
        if ((tid & 63) == 0) red2[2 + (tid >> 6)] = ssum;  // red2[2], red2[3]
    }
    BAR_LGKM();                          // P2 (sc ready for chunk B)

    // PV partial, chunk B
    #pragma unroll
    for (int i = 0; i < 8; ++i) {
        const int r = 128 + sg * 8 + i;
        const int c = d4 ^ (r & 7);
        const float pw = sc[r - 128];
        const float4 x = *(const float4*)&xs[(r << 7) + (c << 2)];
        wacc.x = fmaf(pw, x.x, wacc.x);
        wacc.y = fmaf(pw, x.y, wacc.y);
        wacc.z = fmaf(pw, x.z, wacc.z);
        wacc.w = fmaf(pw, x.w, wacc.w);
    }
    *(float4*)&wp[sg][d4 << 2] = wacc;
    BAR_LGKM();                          // P3 (wp written)

    if (tid < 128) {
        float t = 0.f;
        #pragma unroll
        for (int s2 = 0; s2 < 16; ++s2) t += wp[s2][tid];
        ws[tid] = t;
    }
    BAR_LGKM();                          // P4 (ws ready)

    // out quarter: op[g4][e] = sum_{i<32} ws[g4*32+i] * Wv[g4*32+i][e]
    {
        float acc = 0.f;
        #pragma unroll
        for (int i = 0; i < 32; ++i)
            acc = fmaf(ws[g4 * 32 + i], wvreg[i], acc);  // ws wave-uniform read
        op[g4][e128] = acc;
    }
    BAR_LGKM();                          // P5 (op written)

    if (tid < 128) {
        const float SUM = red2[0] + red2[1] + red2[2] + red2[3];
        const float r = (op[0][tid] + op[1][tid] + op[2][tid] + op[3][tid])
                        * (1.0f / SUM) + bvreg + creg;
        out[(size_t)b * D + h * HD + tid] = r;
    }
}

// ---------------- generic fallback (any window<=256) ----------
__global__ __launch_bounds__(256) void bca_generic(
    const float* __restrict__ content, const float* __restrict__ cache,
    const float* __restrict__ Wq, const float* __restrict__ bq,
    const float* __restrict__ Wk, const float* __restrict__ Wv,
    const float* __restrict__ bv, const float* __restrict__ pos_param_p,
    float* __restrict__ out,
    int B, int T, int D, int H, int S, int window, int cutoff)
{
    constexpr int HD = 128;
    constexpr int XP = HD + 1;
    const int bh = blockIdx.x;
    const int b = bh / H, h = bh % H;
    const int tid = threadIdx.x;

    __shared__ float xs[WINDOW_MAX * XP];
    __shared__ float cnt_s[HD];
    __shared__ float q_s[HD];
    __shared__ float qk_s[HD];
    __shared__ float sc_s[WINDOW_MAX];
    __shared__ float part_s[256];
    __shared__ float wsum_s[HD];
    __shared__ float red_s[4];

    const float* cnt_g = content + (size_t)b * D + (size_t)h * HD;
    if (tid < HD) cnt_s[tid] = cnt_g[tid];

    const int total4 = window * (HD / 4);
    for (int idx = tid; idx < total4; idx += blockDim.x) {
        const int w = idx >> 5, f = idx & 31;
        const int gpos = cutoff + w;
        const float* src = (gpos < T)
            ? (cache + (size_t)b * T * D + (size_t)gpos * D + (size_t)h * HD)
            : cnt_g;
        const float4 v4 = *(const float4*)(src + f * 4);
        float* dst = &xs[w * XP + f * 4];
        dst[0] = v4.x; dst[1] = v4.y; dst[2] = v4.z; dst[3] = v4.w;
    }
    __syncthreads();

    if (tid < HD) {
        const float* wq = Wq + (size_t)h * HD * HD;
        float acc = 0.f;
        #pragma unroll 8
        for (int d = 0; d < HD; ++d) acc = fmaf(cnt_s[d], wq[d * HD + tid], acc);
        q_s[tid] = acc + bq[h * HD + tid];
    }
    __syncthreads();

    if (tid < HD) {
        const float* wk = Wk + (size_t)h * HD * HD + (size_t)tid * HD;
        float acc = 0.f;
        #pragma unroll 8
        for (int e = 0; e < HD; e += 4) {
            const float4 w4 = *(const float4*)(wk + e);
            acc = fmaf(w4.x, q_s[e],     acc);
            acc = fmaf(w4.y, q_s[e + 1], acc);
            acc = fmaf(w4.z, q_s[e + 2], acc);
            acc = fmaf(w4.w, q_s[e + 3], acc);
        }
        qk_s[tid] = acc;
    }
    __syncthreads();

    const float pos_param = pos_param_p[0];
    float score = -INFINITY;
    if (tid < window) {
        float acc = 0.f;
        const float* xr = &xs[tid * XP];
        #pragma unroll 8
        for (int d = 0; d < HD; ++d) acc = fmaf(qk_s[d], xr[d], acc);
        const int gpos = cutoff + tid;
        const int n = (S - 1) - gpos;
        float posb;
        if (n < 16) posb = (float)n;
        else {
            const float lc = 2.0794415416798357f;
            int large = 16 + (int)((logf((float)n / 16.0f) / lc) * 16.0f);
            if (large > 31) large = 31;
            posb = (float)large;
        }
        score = (acc / 11.313708498984761f) - pos_param * posb + NEG;
    }

    float m = score;
    #pragma unroll
    for (int off = 32; off >= 1; off >>= 1) m = fmaxf(m, __shfl_xor(m, off));
    if ((tid & 63) == 0) red_s[tid >> 6] = m;
    __syncthreads();
    const int nw = blockDim.x >> 6;
    float M = red_s[0];
    for (int i = 1; i < nw; ++i) M = fmaxf(M, red_s[i]);

    float p = (tid < window) ? expf(score - M) : 0.f;
    float ssum = p;
    #pragma unroll
    for (int off = 32; off >= 1; off >>= 1) ssum += __shfl_xor(ssum, off);
    __syncthreads();
    if ((tid & 63) == 0) red_s[tid >> 6] = ssum;
    __syncthreads();
    float SUM = 0.f;
    for (int i = 0; i < nw; ++i) SUM += red_s[i];
    const float inv = 1.0f / SUM;
    if (tid < window) sc_s[tid] = p * inv;
    __syncthreads();

    {
        const int d = tid & (HD - 1), half = tid >> 7;
        const int s0 = half * (window >> 1), s1 = s0 + (window >> 1);
        float acc = 0.f;
        for (int s = s0; s < s1; ++s) acc = fmaf(sc_s[s], xs[s * XP + d], acc);
        part_s[tid] = acc;
    }
    __syncthreads();
    if (tid < HD) wsum_s[tid] = part_s[tid] + part_s[tid + HD];
    __syncthreads();

    {
        const int e = tid & (HD - 1), dh = tid >> 7;
        const float* wv = Wv + (size_t)h * HD * HD;
        float acc = 0.f;
        for (int d = dh * 64; d < dh * 64 + 64; ++d)
            acc = fmaf(wsum_s[d], wv[d * HD + e], acc);
        part_s[tid] = acc;
    }
    __syncthreads();
    if (tid < HD) {
        const float r = part_s[tid] + part_s[tid + HD]
                      + bv[h * HD + tid] + cnt_g[tid];
        out[(size_t)b * D + (size_t)h * HD + tid] = r;
    }
}

extern "C" void kernel_launch(void* const* d_in, const int* in_sizes, int n_in,
                              void* d_out, int out_size, void* d_ws, size_t ws_size,
                              hipStream_t stream) {
    // inputs: 0:t 1:content_t 2:time_mask 3:cache 4:speakers 5:Wq 6:bq 7:Wk 8:bk 9:Wv 10:bv 11:pos_param
    const float* content = (const float*)d_in[1];
    const float* cache   = (const float*)d_in[3];
    const float* Wq      = (const float*)d_in[5];
    const float* bq      = (const float*)d_in[6];
    const float* Wk      = (const float*)d_in[7];
    const float* Wv      = (const float*)d_in[9];
    const float* bv      = (const float*)d_in[10];
    const float* posp    = (const float*)d_in[11];

    const int D  = in_sizes[6];
    const int B  = in_sizes[1] / D;
    const int hd = in_sizes[5] / D;
    const int H  = D / hd;
    const int T  = in_sizes[3] / (B * D);
    const int S  = T + 1;
    const int window = (S < WINDOW_MAX) ? S : WINDOW_MAX;
    const int cutoff = S - window;

    if (window == WINDOW_MAX && hd == 128) {
        dim3 grid(H, B), block(512);
        hipLaunchKernelGGL(bca_fast, grid, block, 0, stream,
                           content, cache, Wq, bq, Wk, Wv, bv, posp,
                           (float*)d_out, B, T, D, H, S, cutoff);
    } else {
        dim3 grid(B * H), block(256);
        hipLaunchKernelGGL(bca_generic, grid, block, 0, stream,
                           content, cache, Wq, bq, Wk, Wv, bv, posp,
                           (float*)d_out, B, T, D, H, S, window, cutoff);
    }
}

// Round 8
// 15.428 us; speedup vs baseline: 1.6998x; 1.6998x over previous
//
#include <hip/hip_runtime.h>
#include <math.h>

#define WINDOW_MAX 256
#define NEG -1000000.0f

typedef __attribute__((address_space(1))) const float gfloat;
typedef __attribute__((address_space(3))) float lfloat;

// ---------------- fast path: window==256, hd==128, 512 threads ----------------
// One block per (b,h): grid (H, B) -> same-h blocks share an XCD L2 for weights.
// R7 = R5 structure (best measured) minus two serial-chain links:
//   - no-max softmax: p = exp(score - NEG). (y+NEG)-NEG is exact in fp32 and
//     the constant factor cancels in normalization (verified R6: same absmax).
//     Kills one block-wide reduction + barrier.
//   - Wv prefetch issued AFTER B2 (not before B1): B1's vmcnt(0) drain covers
//     only the 128KB window on S-waves; Wv's 64KB lands under scores/softmax.
// Waves 0-3 (C): Wk->regs, q matvec (Wq streamed), qk. Waves 4-7 (S): window
// via 32x async global_load_lds, then Wv->regs post-B2, then out matvec.
// xs layout: 128 floats/row, 16B-chunk XOR swizzle (lds chunk c = f ^ (row&7))
// -> conflict-free ds ops for staging writes + score reads + wsum reads.
__global__ __launch_bounds__(512, 2) void bca_fast(
    const float* __restrict__ content,   // (B, D)
    const float* __restrict__ cache,     // (B, T, D)
    const float* __restrict__ Wq,        // (H, 128, 128)
    const float* __restrict__ bq,        // (H, 128)
    const float* __restrict__ Wk,        // (H, 128, 128)
    const float* __restrict__ Wv,        // (H, 128, 128)
    const float* __restrict__ bv,        // (H, 128)
    const float* __restrict__ pos_param_p,
    float* __restrict__ out,             // (B, D)
    int B, int T, int D, int H, int S, int cutoff)
{
    constexpr int HD  = 128;
    constexpr int WIN = 256;

    __shared__ float xs[WIN * HD];       // 131072 B, swizzled 16B chunks
    __shared__ float qp[2][HD];          // q partials (g2=0 half includes bq)
    __shared__ float kp[2][HD];          // qk partials
    __shared__ float scp[2][WIN];        // score partials
    __shared__ float sc[WIN];            // UNNORMALIZED softmax weights p
    __shared__ float wp[4][HD];          // weighted-sum partials
    __shared__ float op[2][HD];          // output partials (S-waves)
    __shared__ float red2[8];            // p-sum partials

    const int tid = threadIdx.x;
    const int h = blockIdx.x, b = blockIdx.y;
    const float* cnt_g = content + (size_t)b * D + h * HD;
    const float* cb    = cache + (size_t)b * T * D + h * HD;

    const float pos_param = pos_param_p[0];
    const int e128 = tid & 127;
    const int g4   = tid >> 7;                         // 0..3, wave-uniform
    float creg = 0.f, bvreg = 0.f;
    if (tid < HD) { creg = cnt_g[tid]; bvreg = bv[h * HD + tid]; }

    float wvreg[64];                     // S-waves only, loaded post-B2

    if (tid < 256) {
        // ===== C-waves 0-3 =====
        const int g2 = g4;                             // 0/1
        // Wk prefetch: thread (d=e128, eh=g2) holds Wk[d][g2*64 .. +63]
        float4 wk4[16];
        {
            const float* wkp = Wk + h * HD * HD + e128 * HD + g2 * 64;
            #pragma unroll
            for (int j = 0; j < 16; ++j) wk4[j] = *(const float4*)(wkp + j * 4);
        }
        // q partial: q[e] = sum_d cnt[d] * Wq[d][e] (+ bq on g2==0 half)
        const float* wqp = Wq + h * HD * HD + (g2 * 64) * HD + e128;
        const float* cg  = cnt_g + g2 * 64;            // wave-uniform reads
        float acc = (g2 == 0) ? bq[h * HD + e128] : 0.f;
        #pragma unroll
        for (int i = 0; i < 64; ++i)
            acc = fmaf(cg[i], wqp[i * HD], acc);
        qp[g2][e128] = acc;

        __syncthreads();   // B1: q partials + window staged

        // qk partial: thread (d=e128, eh=g2) over e = g2*64..+63
        float a2 = 0.f;
        #pragma unroll
        for (int j = 0; j < 16; ++j) {
            const float4 q0 = *(const float4*)&qp[0][g2 * 64 + j * 4]; // broadcast
            const float4 q1 = *(const float4*)&qp[1][g2 * 64 + j * 4];
            a2 = fmaf(wk4[j].x, q0.x + q1.x, a2);
            a2 = fmaf(wk4[j].y, q0.y + q1.y, a2);
            a2 = fmaf(wk4[j].z, q0.z + q1.z, a2);
            a2 = fmaf(wk4[j].w, q0.w + q1.w, a2);
        }
        kp[g2][e128] = a2;
    } else {
        // ===== S-waves 4-7: window staging only pre-B1 =====
        // 32 async 1KB global_load_lds per wave. LDS dest linear
        // (base + lane*16); per-lane source pre-swizzled so lds chunk c
        // holds global chunk f = c ^ (row&7).
        const int sw   = (tid >> 6) - 4;               // 0..3
        const int lane = tid & 63;
        #pragma unroll
        for (int i = 0; i < 32; ++i) {
            const int w    = sw * 64 + i * 2;          // wave-uniform row pair
            const int row  = w + (lane >> 5);
            const int f    = (lane & 31) ^ (row & 7);
            const int gpos = cutoff + row;
            const float* src = (gpos < T) ? (cb + (size_t)gpos * D + f * 4)
                                          : (cnt_g + f * 4);
            __builtin_amdgcn_global_load_lds((gfloat*)src, (lfloat*)&xs[w << 7],
                                             16, 0, 0);
        }
        __syncthreads();   // B1 (drains vmcnt -> xs complete)
    }
    __syncthreads();       // B2: kp ready

    // ---- S-waves: issue Wv loads now; they land under scores/softmax ----
    if (tid >= 256) {
        const int half = g4 - 2;                       // 0/1, wave-uniform
        const float* wvp = Wv + h * HD * HD + (half * 64) * HD + e128;
        #pragma unroll
        for (int i = 0; i < 64; ++i) wvreg[i] = wvp[i * HD];
    }

    // ---- scores (512 threads = 256 s x 2 d-halves) ----
    {
        const int s = tid & 255, dh = tid >> 8;        // dh wave-uniform
        const int swz = s & 7;
        float acc = 0.f;
        #pragma unroll
        for (int j = 0; j < 16; ++j) {
            const int c = (dh * 16 + j) ^ swz;
            const float4 x  = *(const float4*)&xs[(s << 7) + (c << 2)];
            const float4 k0 = *(const float4*)&kp[0][dh * 64 + j * 4];  // broadcast
            const float4 k1 = *(const float4*)&kp[1][dh * 64 + j * 4];
            acc = fmaf(x.x, k0.x + k1.x, acc);
            acc = fmaf(x.y, k0.y + k1.y, acc);
            acc = fmaf(x.z, k0.z + k1.z, acc);
            acc = fmaf(x.w, k0.w + k1.w, acc);
        }
        scp[dh][s] = acc;
    }
    __syncthreads();   // B3

    // ---- softmax weights, no max reduction (subtract the constant NEG) ----
    float p = 0.f;
    if (tid < WIN) {
        const float dot = scp[0][tid] + scp[1][tid];
        const int n = (WIN - 1) - tid;                 // distance to query
        float posb;
        if (n < 16) {
            posb = (float)n;
        } else {
            const float lc = 2.0794415416798357f;      // float32(log(8))
            int large = 16 + (int)((logf((float)n / 16.0f) / lc) * 16.0f);
            if (large > 31) large = 31;
            posb = (float)large;
        }
        // time_mask collapses to NEG everywhere (1->0, then 0->NEG); +NEG
        // reproduces the reference's pre-softmax quantization, and
        // (y + NEG) - NEG is exact in fp32; constant factor cancels in 1/SUM.
        const float score = (dot / 11.313708498984761f) - pos_param * posb + NEG;
        p = expf(score - NEG);
        sc[tid] = p;
    }
    float ssum = p;
    #pragma unroll
    for (int off = 32; off >= 1; off >>= 1) ssum += __shfl_xor(ssum, off);
    if ((tid & 63) == 0) red2[tid >> 6] = ssum;
    __syncthreads();   // B5: sc + red2 ready

    // ---- wsum_d = sum_s p_s * x[s][d] (4-way s split, unnormalized) ----
    {
        const int d = e128, sq = g4;                   // sq wave-uniform 0..3
        const int dc = d >> 2, dw = d & 3;
        float acc = 0.f;
        #pragma unroll
        for (int i = 0; i < 64; ++i) {
            const int s2 = sq * 64 + i;
            const int c = dc ^ (s2 & 7);
            acc = fmaf(sc[s2], xs[(s2 << 7) + (c << 2) + dw], acc);
        }
        wp[sq][d] = acc;
    }
    __syncthreads();   // B6

    // ---- out_e = wsum . Wv[:,e]  (S-waves, Wv in their registers) ----
    if (tid >= 256) {
        const int half = g4 - 2;                       // 0/1, wave-uniform
        float acc = 0.f;
        #pragma unroll
        for (int i = 0; i < 64; ++i) {
            const int d2 = half * 64 + i;              // wave-uniform
            const float ws = wp[0][d2] + wp[1][d2] + wp[2][d2] + wp[3][d2];
            acc = fmaf(ws, wvreg[i], acc);
        }
        op[half][e128] = acc;
    }
    __syncthreads();   // B7

    if (tid < HD) {
        float SUM = red2[0];
        #pragma unroll
        for (int i = 1; i < 8; ++i) SUM += red2[i];
        const float r = (op[0][tid] + op[1][tid]) * (1.0f / SUM) + bvreg + creg;
        out[(size_t)b * D + h * HD + tid] = r;
    }
}

// ---------------- generic fallback (any window<=256) ----------
__global__ __launch_bounds__(256) void bca_generic(
    const float* __restrict__ content, const float* __restrict__ cache,
    const float* __restrict__ Wq, const float* __restrict__ bq,
    const float* __restrict__ Wk, const float* __restrict__ Wv,
    const float* __restrict__ bv, const float* __restrict__ pos_param_p,
    float* __restrict__ out,
    int B, int T, int D, int H, int S, int window, int cutoff)
{
    constexpr int HD = 128;
    constexpr int XP = HD + 1;
    const int bh = blockIdx.x;
    const int b = bh / H, h = bh % H;
    const int tid = threadIdx.x;

    __shared__ float xs[WINDOW_MAX * XP];
    __shared__ float cnt_s[HD];
    __shared__ float q_s[HD];
    __shared__ float qk_s[HD];
    __shared__ float sc_s[WINDOW_MAX];
    __shared__ float part_s[256];
    __shared__ float wsum_s[HD];
    __shared__ float red_s[4];

    const float* cnt_g = content + (size_t)b * D + (size_t)h * HD;
    if (tid < HD) cnt_s[tid] = cnt_g[tid];

    const int total4 = window * (HD / 4);
    for (int idx = tid; idx < total4; idx += blockDim.x) {
        const int w = idx >> 5, f = idx & 31;
        const int gpos = cutoff + w;
        const float* src = (gpos < T)
            ? (cache + (size_t)b * T * D + (size_t)gpos * D + (size_t)h * HD)
            : cnt_g;
        const float4 v4 = *(const float4*)(src + f * 4);
        float* dst = &xs[w * XP + f * 4];
        dst[0] = v4.x; dst[1] = v4.y; dst[2] = v4.z; dst[3] = v4.w;
    }
    __syncthreads();

    if (tid < HD) {
        const float* wq = Wq + (size_t)h * HD * HD;
        float acc = 0.f;
        #pragma unroll 8
        for (int d = 0; d < HD; ++d) acc = fmaf(cnt_s[d], wq[d * HD + tid], acc);
        q_s[tid] = acc + bq[h * HD + tid];
    }
    __syncthreads();

    if (tid < HD) {
        const float* wk = Wk + (size_t)h * HD * HD + (size_t)tid * HD;
        float acc = 0.f;
        #pragma unroll 8
        for (int e = 0; e < HD; e += 4) {
            const float4 w4 = *(const float4*)(wk + e);
            acc = fmaf(w4.x, q_s[e],     acc);
            acc = fmaf(w4.y, q_s[e + 1], acc);
            acc = fmaf(w4.z, q_s[e + 2], acc);
            acc = fmaf(w4.w, q_s[e + 3], acc);
        }
        qk_s[tid] = acc;
    }
    __syncthreads();

    const float pos_param = pos_param_p[0];
    float score = -INFINITY;
    if (tid < window) {
        float acc = 0.f;
        const float* xr = &xs[tid * XP];
        #pragma unroll 8
        for (int d = 0; d < HD; ++d) acc = fmaf(qk_s[d], xr[d], acc);
        const int gpos = cutoff + tid;
        const int n = (S - 1) - gpos;
        float posb;
        if (n < 16) posb = (float)n;
        else {
            const float lc = 2.0794415416798357f;
            int large = 16 + (int)((logf((float)n / 16.0f) / lc) * 16.0f);
            if (large > 31) large = 31;
            posb = (float)large;
        }
        score = (acc / 11.313708498984761f) - pos_param * posb + NEG;
    }

    float m = score;
    #pragma unroll
    for (int off = 32; off >= 1; off >>= 1) m = fmaxf(m, __shfl_xor(m, off));
    if ((tid & 63) == 0) red_s[tid >> 6] = m;
    __syncthreads();
    const int nw = blockDim.x >> 6;
    float M = red_s[0];
    for (int i = 1; i < nw; ++i) M = fmaxf(M, red_s[i]);

    float p = (tid < window) ? expf(score - M) : 0.f;
    float ssum = p;
    #pragma unroll
    for (int off = 32; off >= 1; off >>= 1) ssum += __shfl_xor(ssum, off);
    __syncthreads();
    if ((tid & 63) == 0) red_s[tid >> 6] = ssum;
    __syncthreads();
    float SUM = 0.f;
    for (int i = 0; i < nw; ++i) SUM += red_s[i];
    const float inv = 1.0f / SUM;
    if (tid < window) sc_s[tid] = p * inv;
    __syncthreads();

    {
        const int d = tid & (HD - 1), half = tid >> 7;
        const int s0 = half * (window >> 1), s1 = s0 + (window >> 1);
        float acc = 0.f;
        for (int s = s0; s < s1; ++s) acc = fmaf(sc_s[s], xs[s * XP + d], acc);
        part_s[tid] = acc;
    }
    __syncthreads();
    if (tid < HD) wsum_s[tid] = part_s[tid] + part_s[tid + HD];
    __syncthreads();

    {
        const int e = tid & (HD - 1), dh = tid >> 7;
        const float* wv = Wv + (size_t)h * HD * HD;
        float acc = 0.f;
        for (int d = dh * 64; d < dh * 64 + 64; ++d)
            acc = fmaf(wsum_s[d], wv[d * HD + e], acc);
        part_s[tid] = acc;
    }
    __syncthreads();
    if (tid < HD) {
        const float r = part_s[tid] + part_s[tid + HD]
                      + bv[h * HD + tid] + cnt_g[tid];
        out[(size_t)b * D + (size_t)h * HD + tid] = r;
    }
}

extern "C" void kernel_launch(void* const* d_in, const int* in_sizes, int n_in,
                              void* d_out, int out_size, void* d_ws, size_t ws_size,
                              hipStream_t stream) {
    // inputs: 0:t 1:content_t 2:time_mask 3:cache 4:speakers 5:Wq 6:bq 7:Wk 8:bk 9:Wv 10:bv 11:pos_param
    const float* content = (const float*)d_in[1];
    const float* cache   = (const float*)d_in[3];
    const float* Wq      = (const float*)d_in[5];
    const float* bq      = (const float*)d_in[6];
    const float* Wk      = (const float*)d_in[7];
    const float* Wv      = (const float*)d_in[9];
    const float* bv      = (const float*)d_in[10];
    const float* posp    = (const float*)d_in[11];

    const int D  = in_sizes[6];
    const int B  = in_sizes[1] / D;
    const int hd = in_sizes[5] / D;
    const int H  = D / hd;
    const int T  = in_sizes[3] / (B * D);
    const int S  = T + 1;
    const int window = (S < WINDOW_MAX) ? S : WINDOW_MAX;
    const int cutoff = S - window;

    if (window == WINDOW_MAX && hd == 128) {
        dim3 grid(H, B), block(512);
        hipLaunchKernelGGL(bca_fast, grid, block, 0, stream,
                           content, cache, Wq, bq, Wk, Wv, bv, posp,
                           (float*)d_out, B, T, D, H, S, cutoff);
    } else {
        dim3 grid(B * H), block(256);
        hipLaunchKernelGGL(bca_generic, grid, block, 0, stream,
                           content, cache, Wq, bq, Wk, Wv, bv, posp,
                           (float*)d_out, B, T, D, H, S, window, cutoff);
    }
}

// Round 9
// 14.422 us; speedup vs baseline: 1.8184x; 1.0698x over previous
//
#include <hip/hip_runtime.h>
#include <math.h>

#define WINDOW_MAX 256
#define NEG -1000000.0f

typedef __attribute__((address_space(1))) const float gfloat;
typedef __attribute__((address_space(3))) float lfloat;

// ---------------- fast path: window==256, hd==128, 512 threads ----------------
// One block per (b,h): grid (H, B) -> same-h blocks share an XCD L2 for weights.
// R8 = R7 skeleton + b128 PV (R6's verified PV structure):
//   - no-max softmax: p = exp(score - NEG) (exact; constant cancels in 1/SUM)
//   - Wv prefetch issued AFTER B2 on ALL waves (quarter each), landing under
//     the scores phase; out matvec is 4-way.
//   - PV: 512 thr = 32 d-chunks x 16 s-groups, float4 accumulation, b128 LDS
//     reads (was scalar b32 = the last phase above its throughput floor).
// Waves 0-3 (C): Wk->regs, q matvec (Wq streamed), qk. Waves 4-7 (S): window
// via 32x async global_load_lds.
// xs layout: 128 floats/row, 16B-chunk XOR swizzle (lds chunk c = f ^ (row&7)).
__global__ __launch_bounds__(512, 2) void bca_fast(
    const float* __restrict__ content,   // (B, D)
    const float* __restrict__ cache,     // (B, T, D)
    const float* __restrict__ Wq,        // (H, 128, 128)
    const float* __restrict__ bq,        // (H, 128)
    const float* __restrict__ Wk,        // (H, 128, 128)
    const float* __restrict__ Wv,        // (H, 128, 128)
    const float* __restrict__ bv,        // (H, 128)
    const float* __restrict__ pos_param_p,
    float* __restrict__ out,             // (B, D)
    int B, int T, int D, int H, int S, int cutoff)
{
    constexpr int HD  = 128;
    constexpr int WIN = 256;

    __shared__ float xs[WIN * HD];       // 131072 B, swizzled 16B chunks
    __shared__ float qp[2][HD];          // q partials (g2=0 half includes bq)
    __shared__ float kp[2][HD];          // qk partials
    __shared__ float scp[2][WIN];        // score partials
    __shared__ float sc[WIN];            // UNNORMALIZED softmax weights p
    __shared__ float wp[16][HD];         // PV partials (16 s-groups)
    __shared__ float ws[HD];             // unnormalized weighted sum
    __shared__ float op[4][HD];          // output quarter partials
    __shared__ float red2[8];            // p-sum partials

    const int tid = threadIdx.x;
    const int h = blockIdx.x, b = blockIdx.y;
    const float* cnt_g = content + (size_t)b * D + h * HD;
    const float* cb    = cache + (size_t)b * T * D + h * HD;

    const float pos_param = pos_param_p[0];
    const int e128 = tid & 127;
    const int g4   = tid >> 7;                         // 0..3, wave-uniform
    const int d4   = tid & 31;                         // PV: float4 chunk id
    const int sg   = tid >> 5;                         // PV: s-group 0..15
    float creg = 0.f, bvreg = 0.f;
    if (tid < HD) { creg = cnt_g[tid]; bvreg = bv[h * HD + tid]; }

    float wvreg[32];                     // Wv[g4*32+i][e128], loaded post-B2

    if (tid < 256) {
        // ===== C-waves 0-3 =====
        const int g2 = g4;                             // 0/1
        // Wk prefetch: thread (d=e128, eh=g2) holds Wk[d][g2*64 .. +63]
        float4 wk4[16];
        {
            const float* wkp = Wk + h * HD * HD + e128 * HD + g2 * 64;
            #pragma unroll
            for (int j = 0; j < 16; ++j) wk4[j] = *(const float4*)(wkp + j * 4);
        }
        // q partial: q[e] = sum_d cnt[d] * Wq[d][e] (+ bq on g2==0 half)
        const float* wqp = Wq + h * HD * HD + (g2 * 64) * HD + e128;
        const float* cg  = cnt_g + g2 * 64;            // wave-uniform reads
        float acc = (g2 == 0) ? bq[h * HD + e128] : 0.f;
        #pragma unroll
        for (int i = 0; i < 64; ++i)
            acc = fmaf(cg[i], wqp[i * HD], acc);
        qp[g2][e128] = acc;

        __syncthreads();   // B1: q partials + window staged

        // qk partial: thread (d=e128, eh=g2) over e = g2*64..+63
        float a2 = 0.f;
        #pragma unroll
        for (int j = 0; j < 16; ++j) {
            const float4 q0 = *(const float4*)&qp[0][g2 * 64 + j * 4]; // broadcast
            const float4 q1 = *(const float4*)&qp[1][g2 * 64 + j * 4];
            a2 = fmaf(wk4[j].x, q0.x + q1.x, a2);
            a2 = fmaf(wk4[j].y, q0.y + q1.y, a2);
            a2 = fmaf(wk4[j].z, q0.z + q1.z, a2);
            a2 = fmaf(wk4[j].w, q0.w + q1.w, a2);
        }
        kp[g2][e128] = a2;
    } else {
        // ===== S-waves 4-7: window staging only pre-B1 =====
        // 32 async 1KB global_load_lds per wave. LDS dest linear
        // (base + lane*16); per-lane source pre-swizzled so lds chunk c
        // holds global chunk f = c ^ (row&7).
        const int sw   = (tid >> 6) - 4;               // 0..3
        const int lane = tid & 63;
        #pragma unroll
        for (int i = 0; i < 32; ++i) {
            const int w    = sw * 64 + i * 2;          // wave-uniform row pair
            const int row  = w + (lane >> 5);
            const int f    = (lane & 31) ^ (row & 7);
            const int gpos = cutoff + row;
            const float* src = (gpos < T) ? (cb + (size_t)gpos * D + f * 4)
                                          : (cnt_g + f * 4);
            __builtin_amdgcn_global_load_lds((gfloat*)src, (lfloat*)&xs[w << 7],
                                             16, 0, 0);
        }
        __syncthreads();   // B1 (drains vmcnt -> xs complete)
    }
    __syncthreads();       // B2: kp ready

    // ---- all waves: issue Wv quarter now; lands under scores/softmax ----
    {
        const float* wvp = Wv + h * HD * HD + (g4 * 32) * HD + e128;
        #pragma unroll
        for (int i = 0; i < 32; ++i) wvreg[i] = wvp[i * HD];
    }

    // ---- scores (512 threads = 256 s x 2 d-halves) ----
    {
        const int s = tid & 255, dh = tid >> 8;        // dh wave-uniform
        const int swz = s & 7;
        float acc = 0.f;
        #pragma unroll
        for (int j = 0; j < 16; ++j) {
            const int c = (dh * 16 + j) ^ swz;
            const float4 x  = *(const float4*)&xs[(s << 7) + (c << 2)];
            const float4 k0 = *(const float4*)&kp[0][dh * 64 + j * 4];  // broadcast
            const float4 k1 = *(const float4*)&kp[1][dh * 64 + j * 4];
            acc = fmaf(x.x, k0.x + k1.x, acc);
            acc = fmaf(x.y, k0.y + k1.y, acc);
            acc = fmaf(x.z, k0.z + k1.z, acc);
            acc = fmaf(x.w, k0.w + k1.w, acc);
        }
        scp[dh][s] = acc;
    }
    __syncthreads();   // B3

    // ---- softmax weights, no max reduction (subtract the constant NEG) ----
    float p = 0.f;
    if (tid < WIN) {
        const float dot = scp[0][tid] + scp[1][tid];
        const int n = (WIN - 1) - tid;                 // distance to query
        float posb;
        if (n < 16) {
            posb = (float)n;
        } else {
            const float lc = 2.0794415416798357f;      // float32(log(8))
            int large = 16 + (int)((logf((float)n / 16.0f) / lc) * 16.0f);
            if (large > 31) large = 31;
            posb = (float)large;
        }
        // time_mask collapses to NEG everywhere (1->0, then 0->NEG); +NEG
        // reproduces the reference's pre-softmax quantization, and
        // (y + NEG) - NEG is exact in fp32; constant factor cancels in 1/SUM.
        const float score = (dot / 11.313708498984761f) - pos_param * posb + NEG;
        p = expf(score - NEG);
        sc[tid] = p;
    }
    float ssum = p;
    #pragma unroll
    for (int off = 32; off >= 1; off >>= 1) ssum += __shfl_xor(ssum, off);
    if ((tid & 63) == 0) red2[tid >> 6] = ssum;
    __syncthreads();   // B5: sc + red2 ready

    // ---- PV: wsum_d partials, b128 reads (32 d-chunks x 16 s-groups) ----
    {
        float4 wacc = make_float4(0.f, 0.f, 0.f, 0.f);
        #pragma unroll
        for (int i = 0; i < 16; ++i) {
            const int r = sg * 16 + i;
            const int c = d4 ^ (r & 7);
            const float pw = sc[r];                    // broadcast per 32-lane grp
            const float4 x = *(const float4*)&xs[(r << 7) + (c << 2)];
            wacc.x = fmaf(pw, x.x, wacc.x);
            wacc.y = fmaf(pw, x.y, wacc.y);
            wacc.z = fmaf(pw, x.z, wacc.z);
            wacc.w = fmaf(pw, x.w, wacc.w);
        }
        *(float4*)&wp[sg][d4 << 2] = wacc;
    }
    __syncthreads();   // B6 (wp written)

    if (tid < HD) {
        float t = 0.f;
        #pragma unroll
        for (int s2 = 0; s2 < 16; ++s2) t += wp[s2][tid];   // 2 lanes/bank: free
        ws[tid] = t;
    }
    __syncthreads();   // B6b (ws ready)

    // ---- out quarter: op[g4][e] = sum_{i<32} ws[g4*32+i] * Wv[g4*32+i][e] ----
    {
        float acc = 0.f;
        #pragma unroll
        for (int i = 0; i < 32; ++i)
            acc = fmaf(ws[g4 * 32 + i], wvreg[i], acc);     // ws broadcast read
        op[g4][e128] = acc;
    }
    __syncthreads();   // B7

    if (tid < HD) {
        float SUM = red2[0];
        #pragma unroll
        for (int i = 1; i < 8; ++i) SUM += red2[i];
        const float r = (op[0][tid] + op[1][tid] + op[2][tid] + op[3][tid])
                        * (1.0f / SUM) + bvreg + creg;
        out[(size_t)b * D + h * HD + tid] = r;
    }
}

// ---------------- generic fallback (any window<=256) ----------
__global__ __launch_bounds__(256) void bca_generic(
    const float* __restrict__ content, const float* __restrict__ cache,
    const float* __restrict__ Wq, const float* __restrict__ bq,
    const float* __restrict__ Wk, const float* __restrict__ Wv,
    const float* __restrict__ bv, const float* __restrict__ pos_param_p,
    float* __restrict__ out,
    int B, int T, int D, int H, int S, int window, int cutoff)
{
    constexpr int HD = 128;
    constexpr int XP = HD + 1;
    const int bh = blockIdx.x;
    const int b = bh / H, h = bh % H;
    const int tid = threadIdx.x;

    __shared__ float xs[WINDOW_MAX * XP];
    __shared__ float cnt_s[HD];
    __shared__ float q_s[HD];
    __shared__ float qk_s[HD];
    __shared__ float sc_s[WINDOW_MAX];
    __shared__ float part_s[256];
    __shared__ float wsum_s[HD];
    __shared__ float red_s[4];

    const float* cnt_g = content + (size_t)b * D + (size_t)h * HD;
    if (tid < HD) cnt_s[tid] = cnt_g[tid];

    const int total4 = window * (HD / 4);
    for (int idx = tid; idx < total4; idx += blockDim.x) {
        const int w = idx >> 5, f = idx & 31;
        const int gpos = cutoff + w;
        const float* src = (gpos < T)
            ? (cache + (size_t)b * T * D + (size_t)gpos * D + (size_t)h * HD)
            : cnt_g;
        const float4 v4 = *(const float4*)(src + f * 4);
        float* dst = &xs[w * XP + f * 4];
        dst[0] = v4.x; dst[1] = v4.y; dst[2] = v4.z; dst[3] = v4.w;
    }
    __syncthreads();

    if (tid < HD) {
        const float* wq = Wq + (size_t)h * HD * HD;
        float acc = 0.f;
        #pragma unroll 8
        for (int d = 0; d < HD; ++d) acc = fmaf(cnt_s[d], wq[d * HD + tid], acc);
        q_s[tid] = acc + bq[h * HD + tid];
    }
    __syncthreads();

    if (tid < HD) {
        const float* wk = Wk + (size_t)h * HD * HD + (size_t)tid * HD;
        float acc = 0.f;
        #pragma unroll 8
        for (int e = 0; e < HD; e += 4) {
            const float4 w4 = *(const float4*)(wk + e);
            acc = fmaf(w4.x, q_s[e],     acc);
            acc = fmaf(w4.y, q_s[e + 1], acc);
            acc = fmaf(w4.z, q_s[e + 2], acc);
            acc = fmaf(w4.w, q_s[e + 3], acc);
        }
        qk_s[tid] = acc;
    }
    __syncthreads();

    const float pos_param = pos_param_p[0];
    float score = -INFINITY;
    if (tid < window) {
        float acc = 0.f;
        const float* xr = &xs[tid * XP];
        #pragma unroll 8
        for (int d = 0; d < HD; ++d) acc = fmaf(qk_s[d], xr[d], acc);
        const int gpos = cutoff + tid;
        const int n = (S - 1) - gpos;
        float posb;
        if (n < 16) posb = (float)n;
        else {
            const float lc = 2.0794415416798357f;
            int large = 16 + (int)((logf((float)n / 16.0f) / lc) * 16.0f);
            if (large > 31) large = 31;
            posb = (float)large;
        }
        score = (acc / 11.313708498984761f) - pos_param * posb + NEG;
    }

    float m = score;
    #pragma unroll
    for (int off = 32; off >= 1; off >>= 1) m = fmaxf(m, __shfl_xor(m, off));
    if ((tid & 63) == 0) red_s[tid >> 6] = m;
    __syncthreads();
    const int nw = blockDim.x >> 6;
    float M = red_s[0];
    for (int i = 1; i < nw; ++i) M = fmaxf(M, red_s[i]);

    float p = (tid < window) ? expf(score - M) : 0.f;
    float ssum = p;
    #pragma unroll
    for (int off = 32; off >= 1; off >>= 1) ssum += __shfl_xor(ssum, off);
    __syncthreads();
    if ((tid & 63) == 0) red_s[tid >> 6] = ssum;
    __syncthreads();
    float SUM = 0.f;
    for (int i = 0; i < nw; ++i) SUM += red_s[i];
    const float inv = 1.0f / SUM;
    if (tid < window) sc_s[tid] = p * inv;
    __syncthreads();

    {
        const int d = tid & (HD - 1), half = tid >> 7;
        const int s0 = half * (window >> 1), s1 = s0 + (window >> 1);
        float acc = 0.f;
        for (int s = s0; s < s1; ++s) acc = fmaf(sc_s[s], xs[s * XP + d], acc);
        part_s[tid] = acc;
    }
    __syncthreads();
    if (tid < HD) wsum_s[tid] = part_s[tid] + part_s[tid + HD];
    __syncthreads();

    {
        const int e = tid & (HD - 1), dh = tid >> 7;
        const float* wv = Wv + (size_t)h * HD * HD;
        float acc = 0.f;
        for (int d = dh * 64; d < dh * 64 + 64; ++d)
            acc = fmaf(wsum_s[d], wv[d * HD + e], acc);
        part_s[tid] = acc;
    }
    __syncthreads();
    if (tid < HD) {
        const float r = part_s[tid] + part_s[tid + HD]
                      + bv[h * HD + tid] + cnt_g[tid];
        out[(size_t)b * D + (size_t)h * HD + tid] = r;
    }
}

extern "C" void kernel_launch(void* const* d_in, const int* in_sizes, int n_in,
                              void* d_out, int out_size, void* d_ws, size_t ws_size,
                              hipStream_t stream) {
    // inputs: 0:t 1:content_t 2:time_mask 3:cache 4:speakers 5:Wq 6:bq 7:Wk 8:bk 9:Wv 10:bv 11:pos_param
    const float* content = (const float*)d_in[1];
    const float* cache   = (const float*)d_in[3];
    const float* Wq      = (const float*)d_in[5];
    const float* bq      = (const float*)d_in[6];
    const float* Wk      = (const float*)d_in[7];
    const float* Wv      = (const float*)d_in[9];
    const float* bv      = (const float*)d_in[10];
    const float* posp    = (const float*)d_in[11];

    const int D  = in_sizes[6];
    const int B  = in_sizes[1] / D;
    const int hd = in_sizes[5] / D;
    const int H  = D / hd;
    const int T  = in_sizes[3] / (B * D);
    const int S  = T + 1;
    const int window = (S < WINDOW_MAX) ? S : WINDOW_MAX;
    const int cutoff = S - window;

    if (window == WINDOW_MAX && hd == 128) {
        dim3 grid(H, B), block(512);
        hipLaunchKernelGGL(bca_fast, grid, block, 0, stream,
                           content, cache, Wq, bq, Wk, Wv, bv, posp,
                           (float*)d_out, B, T, D, H, S, cutoff);
    } else {
        dim3 grid(B * H), block(256);
        hipLaunchKernelGGL(bca_generic, grid, block, 0, stream,
                           content, cache, Wq, bq, Wk, Wv, bv, posp,
                           (float*)d_out, B, T, D, H, S, window, cutoff);
    }
}

// Round 10
// 14.290 us; speedup vs baseline: 1.8352x; 1.0092x over previous
//
#include <hip/hip_runtime.h>
#include <math.h>

#define WINDOW_MAX 256
#define NEG -1000000.0f

typedef __attribute__((address_space(1))) const float gfloat;
typedef __attribute__((address_space(3))) float lfloat;

// ---------------- fast path: window==256, hd==128, 512 threads ----------------
// One block per (b,h): grid (H, B) -> same-h blocks share an XCD L2 for weights.
// R9 = R8 + LDS-instruction diet on the two hot phases:
//   - kfull[d] = kp[0][d]+kp[1][d] precomputed once (B2b) -> scores does 2
//     ds_read_b128 per j instead of 3 (the kp-sum was recomputed by every
//     wave every iteration; LDS pipe is per-CU and was the phase floor).
//   - PV reads sc[] as float4 (4 instrs/thread instead of 16 scalar).
// Everything else identical to R8 (verified absmax 9.77e-4).
__global__ __launch_bounds__(512, 2) void bca_fast(
    const float* __restrict__ content,   // (B, D)
    const float* __restrict__ cache,     // (B, T, D)
    const float* __restrict__ Wq,        // (H, 128, 128)
    const float* __restrict__ bq,        // (H, 128)
    const float* __restrict__ Wk,        // (H, 128, 128)
    const float* __restrict__ Wv,        // (H, 128, 128)
    const float* __restrict__ bv,        // (H, 128)
    const float* __restrict__ pos_param_p,
    float* __restrict__ out,             // (B, D)
    int B, int T, int D, int H, int S, int cutoff)
{
    constexpr int HD  = 128;
    constexpr int WIN = 256;

    __shared__ float xs[WIN * HD];       // 131072 B, swizzled 16B chunks
    __shared__ float qp[2][HD];          // q partials (g2=0 half includes bq)
    __shared__ float kp[2][HD];          // qk partials
    __shared__ float kfull[HD];          // kp[0]+kp[1]
    __shared__ float scp[2][WIN];        // score partials
    __shared__ float sc[WIN];            // UNNORMALIZED softmax weights p
    __shared__ float wp[16][HD];         // PV partials (16 s-groups)
    __shared__ float ws[HD];             // unnormalized weighted sum
    __shared__ float op[4][HD];          // output quarter partials
    __shared__ float red2[8];            // p-sum partials

    const int tid = threadIdx.x;
    const int h = blockIdx.x, b = blockIdx.y;
    const float* cnt_g = content + (size_t)b * D + h * HD;
    const float* cb    = cache + (size_t)b * T * D + h * HD;

    const float pos_param = pos_param_p[0];
    const int e128 = tid & 127;
    const int g4   = tid >> 7;                         // 0..3, wave-uniform
    const int d4   = tid & 31;                         // PV: float4 chunk id
    const int sg   = tid >> 5;                         // PV: s-group 0..15
    float creg = 0.f, bvreg = 0.f;
    if (tid < HD) { creg = cnt_g[tid]; bvreg = bv[h * HD + tid]; }

    float wvreg[32];                     // Wv[g4*32+i][e128], loaded post-B2

    if (tid < 256) {
        // ===== C-waves 0-3 =====
        const int g2 = g4;                             // 0/1
        // Wk prefetch: thread (d=e128, eh=g2) holds Wk[d][g2*64 .. +63]
        float4 wk4[16];
        {
            const float* wkp = Wk + h * HD * HD + e128 * HD + g2 * 64;
            #pragma unroll
            for (int j = 0; j < 16; ++j) wk4[j] = *(const float4*)(wkp + j * 4);
        }
        // q partial: q[e] = sum_d cnt[d] * Wq[d][e] (+ bq on g2==0 half)
        const float* wqp = Wq + h * HD * HD + (g2 * 64) * HD + e128;
        const float* cg  = cnt_g + g2 * 64;            // wave-uniform reads
        float acc = (g2 == 0) ? bq[h * HD + e128] : 0.f;
        #pragma unroll
        for (int i = 0; i < 64; ++i)
            acc = fmaf(cg[i], wqp[i * HD], acc);
        qp[g2][e128] = acc;

        __syncthreads();   // B1: q partials + window staged

        // qk partial: thread (d=e128, eh=g2) over e = g2*64..+63
        float a2 = 0.f;
        #pragma unroll
        for (int j = 0; j < 16; ++j) {
            const float4 q0 = *(const float4*)&qp[0][g2 * 64 + j * 4]; // broadcast
            const float4 q1 = *(const float4*)&qp[1][g2 * 64 + j * 4];
            a2 = fmaf(wk4[j].x, q0.x + q1.x, a2);
            a2 = fmaf(wk4[j].y, q0.y + q1.y, a2);
            a2 = fmaf(wk4[j].z, q0.z + q1.z, a2);
            a2 = fmaf(wk4[j].w, q0.w + q1.w, a2);
        }
        kp[g2][e128] = a2;
    } else {
        // ===== S-waves 4-7: window staging only pre-B1 =====
        // 32 async 1KB global_load_lds per wave. LDS dest linear
        // (base + lane*16); per-lane source pre-swizzled so lds chunk c
        // holds global chunk f = c ^ (row&7).
        const int sw   = (tid >> 6) - 4;               // 0..3
        const int lane = tid & 63;
        #pragma unroll
        for (int i = 0; i < 32; ++i) {
            const int w    = sw * 64 + i * 2;          // wave-uniform row pair
            const int row  = w + (lane >> 5);
            const int f    = (lane & 31) ^ (row & 7);
            const int gpos = cutoff + row;
            const float* src = (gpos < T) ? (cb + (size_t)gpos * D + f * 4)
                                          : (cnt_g + f * 4);
            __builtin_amdgcn_global_load_lds((gfloat*)src, (lfloat*)&xs[w << 7],
                                             16, 0, 0);
        }
        __syncthreads();   // B1 (drains vmcnt -> xs complete)
    }
    __syncthreads();       // B2: kp ready

    // ---- all waves: issue Wv quarter now; lands under scores/softmax ----
    {
        const float* wvp = Wv + h * HD * HD + (g4 * 32) * HD + e128;
        #pragma unroll
        for (int i = 0; i < 32; ++i) wvreg[i] = wvp[i * HD];
    }

    // ---- kfull = kp[0] + kp[1], once (saves a ds_read per j in scores) ----
    if (tid < HD) kfull[tid] = kp[0][tid] + kp[1][tid];
    __syncthreads();   // B2b

    // ---- scores (512 threads = 256 s x 2 d-halves) ----
    {
        const int s = tid & 255, dh = tid >> 8;        // dh wave-uniform
        const int swz = s & 7;
        float acc = 0.f;
        #pragma unroll
        for (int j = 0; j < 16; ++j) {
            const int c = (dh * 16 + j) ^ swz;
            const float4 x  = *(const float4*)&xs[(s << 7) + (c << 2)];
            const float4 kf = *(const float4*)&kfull[dh * 64 + j * 4]; // broadcast
            acc = fmaf(x.x, kf.x, acc);
            acc = fmaf(x.y, kf.y, acc);
            acc = fmaf(x.z, kf.z, acc);
            acc = fmaf(x.w, kf.w, acc);
        }
        scp[dh][s] = acc;
    }
    __syncthreads();   // B3

    // ---- softmax weights, no max reduction (subtract the constant NEG) ----
    float p = 0.f;
    if (tid < WIN) {
        const float dot = scp[0][tid] + scp[1][tid];
        const int n = (WIN - 1) - tid;                 // distance to query
        float posb;
        if (n < 16) {
            posb = (float)n;
        } else {
            const float lc = 2.0794415416798357f;      // float32(log(8))
            int large = 16 + (int)((logf((float)n / 16.0f) / lc) * 16.0f);
            if (large > 31) large = 31;
            posb = (float)large;
        }
        // time_mask collapses to NEG everywhere (1->0, then 0->NEG); +NEG
        // reproduces the reference's pre-softmax quantization, and
        // (y + NEG) - NEG is exact in fp32; constant factor cancels in 1/SUM.
        const float score = (dot / 11.313708498984761f) - pos_param * posb + NEG;
        p = expf(score - NEG);
        sc[tid] = p;
    }
    float ssum = p;
    #pragma unroll
    for (int off = 32; off >= 1; off >>= 1) ssum += __shfl_xor(ssum, off);
    if ((tid & 63) == 0) red2[tid >> 6] = ssum;
    __syncthreads();   // B5: sc + red2 ready

    // ---- PV: wsum_d partials, b128 reads (32 d-chunks x 16 s-groups) ----
    {
        float4 wacc = make_float4(0.f, 0.f, 0.f, 0.f);
        #pragma unroll
        for (int ii = 0; ii < 4; ++ii) {
            const float4 ps = *(const float4*)&sc[sg * 16 + ii * 4]; // broadcast
            const float pw[4] = { ps.x, ps.y, ps.z, ps.w };
            #pragma unroll
            for (int k = 0; k < 4; ++k) {
                const int r = sg * 16 + ii * 4 + k;
                const int c = d4 ^ (r & 7);
                const float4 x = *(const float4*)&xs[(r << 7) + (c << 2)];
                wacc.x = fmaf(pw[k], x.x, wacc.x);
                wacc.y = fmaf(pw[k], x.y, wacc.y);
                wacc.z = fmaf(pw[k], x.z, wacc.z);
                wacc.w = fmaf(pw[k], x.w, wacc.w);
            }
        }
        *(float4*)&wp[sg][d4 << 2] = wacc;
    }
    __syncthreads();   // B6 (wp written)

    if (tid < HD) {
        float t = 0.f;
        #pragma unroll
        for (int s2 = 0; s2 < 16; ++s2) t += wp[s2][tid];   // 2 lanes/bank: free
        ws[tid] = t;
    }
    __syncthreads();   // B6b (ws ready)

    // ---- out quarter: op[g4][e] = sum_{i<32} ws[g4*32+i] * Wv[g4*32+i][e] ----
    {
        float acc = 0.f;
        #pragma unroll
        for (int i = 0; i < 32; ++i)
            acc = fmaf(ws[g4 * 32 + i], wvreg[i], acc);     // ws broadcast read
        op[g4][e128] = acc;
    }
    __syncthreads();   // B7

    if (tid < HD) {
        float SUM = red2[0];
        #pragma unroll
        for (int i = 1; i < 8; ++i) SUM += red2[i];
        const float r = (op[0][tid] + op[1][tid] + op[2][tid] + op[3][tid])
                        * (1.0f / SUM) + bvreg + creg;
        out[(size_t)b * D + h * HD + tid] = r;
    }
}

// ---------------- generic fallback (any window<=256) ----------
__global__ __launch_bounds__(256) void bca_generic(
    const float* __restrict__ content, const float* __restrict__ cache,
    const float* __restrict__ Wq, const float* __restrict__ bq,
    const float* __restrict__ Wk, const float* __restrict__ Wv,
    const float* __restrict__ bv, const float* __restrict__ pos_param_p,
    float* __restrict__ out,
    int B, int T, int D, int H, int S, int window, int cutoff)
{
    constexpr int HD = 128;
    constexpr int XP = HD + 1;
    const int bh = blockIdx.x;
    const int b = bh / H, h = bh % H;
    const int tid = threadIdx.x;

    __shared__ float xs[WINDOW_MAX * XP];
    __shared__ float cnt_s[HD];
    __shared__ float q_s[HD];
    __shared__ float qk_s[HD];
    __shared__ float sc_s[WINDOW_MAX];
    __shared__ float part_s[256];
    __shared__ float wsum_s[HD];
    __shared__ float red_s[4];

    const float* cnt_g = content + (size_t)b * D + (size_t)h * HD;
    if (tid < HD) cnt_s[tid] = cnt_g[tid];

    const int total4 = window * (HD / 4);
    for (int idx = tid; idx < total4; idx += blockDim.x) {
        const int w = idx >> 5, f = idx & 31;
        const int gpos = cutoff + w;
        const float* src = (gpos < T)
            ? (cache + (size_t)b * T * D + (size_t)gpos * D + (size_t)h * HD)
            : cnt_g;
        const float4 v4 = *(const float4*)(src + f * 4);
        float* dst = &xs[w * XP + f * 4];
        dst[0] = v4.x; dst[1] = v4.y; dst[2] = v4.z; dst[3] = v4.w;
    }
    __syncthreads();

    if (tid < HD) {
        const float* wq = Wq + (size_t)h * HD * HD;
        float acc = 0.f;
        #pragma unroll 8
        for (int d = 0; d < HD; ++d) acc = fmaf(cnt_s[d], wq[d * HD + tid], acc);
        q_s[tid] = acc + bq[h * HD + tid];
    }
    __syncthreads();

    if (tid < HD) {
        const float* wk = Wk + (size_t)h * HD * HD + (size_t)tid * HD;
        float acc = 0.f;
        #pragma unroll 8
        for (int e = 0; e < HD; e += 4) {
            const float4 w4 = *(const float4*)(wk + e);
            acc = fmaf(w4.x, q_s[e],     acc);
            acc = fmaf(w4.y, q_s[e + 1], acc);
            acc = fmaf(w4.z, q_s[e + 2], acc);
            acc = fmaf(w4.w, q_s[e + 3], acc);
        }
        qk_s[tid] = acc;
    }
    __syncthreads();

    const float pos_param = pos_param_p[0];
    float score = -INFINITY;
    if (tid < window) {
        float acc = 0.f;
        const float* xr = &xs[tid * XP];
        #pragma unroll 8
        for (int d = 0; d < HD; ++d) acc = fmaf(qk_s[d], xr[d], acc);
        const int gpos = cutoff + tid;
        const int n = (S - 1) - gpos;
        float posb;
        if (n < 16) posb = (float)n;
        else {
            const float lc = 2.0794415416798357f;
            int large = 16 + (int)((logf((float)n / 16.0f) / lc) * 16.0f);
            if (large > 31) large = 31;
            posb = (float)large;
        }
        score = (acc / 11.313708498984761f) - pos_param * posb + NEG;
    }

    float m = score;
    #pragma unroll
    for (int off = 32; off >= 1; off >>= 1) m = fmaxf(m, __shfl_xor(m, off));
    if ((tid & 63) == 0) red_s[tid >> 6] = m;
    __syncthreads();
    const int nw = blockDim.x >> 6;
    float M = red_s[0];
    for (int i = 1; i < nw; ++i) M = fmaxf(M, red_s[i]);

    float p = (tid < window) ? expf(score - M) : 0.f;
    float ssum = p;
    #pragma unroll
    for (int off = 32; off >= 1; off >>= 1) ssum += __shfl_xor(ssum, off);
    __syncthreads();
    if ((tid & 63) == 0) red_s[tid >> 6] = ssum;
    __syncthreads();
    float SUM = 0.f;
    for (int i = 0; i < nw; ++i) SUM += red_s[i];
    const float inv = 1.0f / SUM;
    if (tid < window) sc_s[tid] = p * inv;
    __syncthreads();

    {
        const int d = tid & (HD - 1), half = tid >> 7;
        const int s0 = half * (window >> 1), s1 = s0 + (window >> 1);
        float acc = 0.f;
        for (int s = s0; s < s1; ++s) acc = fmaf(sc_s[s], xs[s * XP + d], acc);
        part_s[tid] = acc;
    }
    __syncthreads();
    if (tid < HD) wsum_s[tid] = part_s[tid] + part_s[tid + HD];
    __syncthreads();

    {
        const int e = tid & (HD - 1), dh = tid >> 7;
        const float* wv = Wv + (size_t)h * HD * HD;
        float acc = 0.f;
        for (int d = dh * 64; d < dh * 64 + 64; ++d)
            acc = fmaf(wsum_s[d], wv[d * HD + e], acc);
        part_s[tid] = acc;
    }
    __syncthreads();
    if (tid < HD) {
        const float r = part_s[tid] + part_s[tid + HD]
                      + bv[h * HD + tid] + cnt_g[tid];
        out[(size_t)b * D + (size_t)h * HD + tid] = r;
    }
}

extern "C" void kernel_launch(void* const* d_in, const int* in_sizes, int n_in,
                              void* d_out, int out_size, void* d_ws, size_t ws_size,
                              hipStream_t stream) {
    // inputs: 0:t 1:content_t 2:time_mask 3:cache 4:speakers 5:Wq 6:bq 7:Wk 8:bk 9:Wv 10:bv 11:pos_param
    const float* content = (const float*)d_in[1];
    const float* cache   = (const float*)d_in[3];
    const float* Wq      = (const float*)d_in[5];
    const float* bq      = (const float*)d_in[6];
    const float* Wk      = (const float*)d_in[7];
    const float* Wv      = (const float*)d_in[9];
    const float* bv      = (const float*)d_in[10];
    const float* posp    = (const float*)d_in[11];

    const int D  = in_sizes[6];
    const int B  = in_sizes[1] / D;
    const int hd = in_sizes[5] / D;
    const int H  = D / hd;
    const int T  = in_sizes[3] / (B * D);
    const int S  = T + 1;
    const int window = (S < WINDOW_MAX) ? S : WINDOW_MAX;
    const int cutoff = S - window;

    if (window == WINDOW_MAX && hd == 128) {
        dim3 grid(H, B), block(512);
        hipLaunchKernelGGL(bca_fast, grid, block, 0, stream,
                           content, cache, Wq, bq, Wk, Wv, bv, posp,
                           (float*)d_out, B, T, D, H, S, cutoff);
    } else {
        dim3 grid(B * H), block(256);
        hipLaunchKernelGGL(bca_generic, grid, block, 0, stream,
                           content, cache, Wq, bq, Wk, Wv, bv, posp,
                           (float*)d_out, B, T, D, H, S, window, cutoff);
    }
}